// Round 2
// baseline (244.631 us; speedup 1.0000x reference)
//
#include <hip/hip_runtime.h>

#define D 4096

// One WAVE per row. Lane holds 64 elements: idx = k*256 + lane*4 + j,
// k in [0,16) (reg bits 8..11), lane bits 2..7, j in [0,4) (reg bits 0..1).
// H4096 = H4(j, regs) (x) H64(lane, shuffles) (x) H16(k, regs).
// FWHT butterflies over disjoint bit groups commute; data stays positional.
// No LDS storage, no barriers, fully coalesced dwordx4 loads AND stores.
__global__ __launch_bounds__(256, 4) void fwht_kernel(const float* __restrict__ x,
                                                      const float* __restrict__ signs,
                                                      float* __restrict__ out,
                                                      int rows) {
    const int lane = threadIdx.x & 63;
    const int wid = threadIdx.x >> 6;
    const long row = (long)blockIdx.x * 4 + wid;
    if (row >= rows) return;

    const float4* __restrict__ xv = (const float4*)(x + row * (long)D);
    const float4* __restrict__ sv = (const float4*)signs;
    float4* __restrict__ ov = (float4*)(out + row * (long)D);

    float v[64];

    // ---- load + sign multiply: 16 dwordx4, 1 KB per wave-instruction ----
#pragma unroll
    for (int k = 0; k < 16; k++) {
        float4 a = xv[k * 64 + lane];
        float4 s = sv[k * 64 + lane];
        v[4 * k + 0] = a.x * s.x;
        v[4 * k + 1] = a.y * s.y;
        v[4 * k + 2] = a.z * s.z;
        v[4 * k + 3] = a.w * s.w;
    }

    // ---- H4 over j (in registers) ----
#pragma unroll
    for (int k = 0; k < 16; k++) {
        float a0 = v[4 * k + 0], a1 = v[4 * k + 1];
        float a2 = v[4 * k + 2], a3 = v[4 * k + 3];
        float b0 = a0 + a1, b1 = a0 - a1;
        float b2 = a2 + a3, b3 = a2 - a3;
        v[4 * k + 0] = b0 + b2;
        v[4 * k + 1] = b1 + b3;
        v[4 * k + 2] = b0 - b2;
        v[4 * k + 3] = b1 - b3;
    }

    // ---- H64 over lanes (6 shuffle stages, 64 independent values each) ----
#pragma unroll
    for (int s = 1; s < 64; s <<= 1) {
        const float sgn = (lane & s) ? -1.0f : 1.0f;
#pragma unroll
        for (int i = 0; i < 64; i++) {
            float p = __shfl_xor(v[i], s, 64);
            v[i] = fmaf(sgn, v[i], p);
        }
    }

    // ---- H16 over k (in registers, stride 4) ----
#pragma unroll
    for (int s = 1; s < 16; s <<= 1) {
#pragma unroll
        for (int k = 0; k < 16; k++) {
            if (!(k & s)) {
#pragma unroll
                for (int j = 0; j < 4; j++) {
                    float a = v[4 * k + j];
                    float b = v[4 * (k ^ s) + j];
                    v[4 * k + j] = a + b;
                    v[4 * (k ^ s) + j] = a - b;
                }
            }
        }
    }

    // ---- scale + store: 16 dwordx4, fully coalesced ----
    const float scale = 1.0f / 64.0f;  // 4096^-0.5
#pragma unroll
    for (int k = 0; k < 16; k++) {
        float4 r;
        r.x = v[4 * k + 0] * scale;
        r.y = v[4 * k + 1] * scale;
        r.z = v[4 * k + 2] * scale;
        r.w = v[4 * k + 3] * scale;
        ov[k * 64 + lane] = r;
    }
}

extern "C" void kernel_launch(void* const* d_in, const int* in_sizes, int n_in,
                              void* d_out, int out_size, void* d_ws, size_t ws_size,
                              hipStream_t stream) {
    const float* x = (const float*)d_in[0];
    const float* signs = (const float*)d_in[1];
    float* out = (float*)d_out;
    const int rows = in_sizes[0] / D;  // 8192
    const int blocks = (rows + 3) / 4;  // 4 waves (rows) per 256-thread block
    fwht_kernel<<<dim3(blocks), dim3(256), 0, stream>>>(x, signs, out, rows);
}

// Round 3
// 229.527 us; speedup vs baseline: 1.0658x; 1.0658x over previous
//
#include <hip/hip_runtime.h>

#define D 4096

// Full 64-point Walsh-Hadamard on a register array (strides 1..32).
__device__ __forceinline__ void fwht64_reg(float v[64]) {
#pragma unroll
    for (int s = 1; s < 64; s <<= 1) {
#pragma unroll
        for (int i = 0; i < 64; i++) {
            if (!(i & s)) {
                float a = v[i], b = v[i ^ s];
                v[i]     = a + b;
                v[i ^ s] = a - b;
            }
        }
    }
}

// One WAVE (= one 64-thread block) per row. H4096 = H64 (x) H64.
// Reg m = k*4+j holds element i = k*256 + lane*4 + j  (k: bits 8-11, lane:
// bits 2-7, j: bits 0-1). fwht64 over m covers bits {0,1,8..11}; an in-wave
// LDS transpose swaps lane bits with reg bits; second fwht64 covers bits 2-7.
// LDS byte addr for element i: swz(i) = (k<<10) + ((l<<4) ^ (k<<4)) + (j<<2)
// (XOR-k on addr bits 4-7). Both the contiguous b128 pattern and the
// transpose-gather pattern land at exactly 2-way bank aliasing (free).
// Single wave per block -> no __syncthreads anywhere; DS ops are wave-ordered.
__global__ __launch_bounds__(64, 2) void fwht_kernel(const float* __restrict__ x,
                                                     const float* __restrict__ signs,
                                                     float* __restrict__ out) {
    __shared__ float lds[D];  // 16 KB per wave
    char* const ldsb = (char*)lds;

    const int lane = threadIdx.x;  // 0..63
    const long row = blockIdx.x;

    const float4* __restrict__ xv = (const float4*)(x + row * (long)D);
    const float4* __restrict__ sv = (const float4*)signs;
    float4* __restrict__ ov = (float4*)(out + row * (long)D);

    float v[64];

    // ---- load + sign: 16 coalesced dwordx4 (16 B/lane) ----
#pragma unroll
    for (int k = 0; k < 16; k++) {
        float4 a = xv[k * 64 + lane];
        float4 s = sv[k * 64 + lane];
        v[4 * k + 0] = a.x * s.x;
        v[4 * k + 1] = a.y * s.y;
        v[4 * k + 2] = a.z * s.z;
        v[4 * k + 3] = a.w * s.w;
    }

    // ---- phase A: H64 over reg bits (element bits 0,1,8..11) ----
    fwht64_reg(v);

    // ---- T1 write (pattern W): 16 x ds_write_b128, swizzled ----
    const int lo4 = (lane & 15) << 4;   // bits 4-7 of addr (XORed with k)
    const int hi2 = (lane & 48) << 4;   // bits 8-9 of addr (additive)
#pragma unroll
    for (int k = 0; k < 16; k++) {
        const int addr = (k << 10) + ((lo4 ^ (k << 4)) + hi2);
        *(float4*)(ldsb + addr) =
            make_float4(v[4 * k + 0], v[4 * k + 1], v[4 * k + 2], v[4 * k + 3]);
    }

    // ---- T1 read (pattern R): this lane becomes (k,j) = (lane>>2, lane&3);
    //      reg r = old lane index l. 64 x ds_read_b32, 2-way banks. ----
    const int kk = lane >> 2, jj = lane & 3;
    const int rbase = (kk << 10) + (jj << 2);
    const int kx = kk << 4;
#pragma unroll
    for (int l = 0; l < 64; l++)
        v[l] = *(const float*)(ldsb + rbase + (((l << 4) ^ kx)));

    // ---- phase B: H64 over old lane bits (element bits 2..7) ----
    fwht64_reg(v);

    // ---- T2 write (pattern R) ----
#pragma unroll
    for (int l = 0; l < 64; l++)
        *(float*)(ldsb + rbase + (((l << 4) ^ kx))) = v[l];

    // ---- T2 read (pattern W) + scale + coalesced dwordx4 store ----
    const float scale = 1.0f / 64.0f;  // 4096^-0.5
#pragma unroll
    for (int k = 0; k < 16; k++) {
        const int addr = (k << 10) + ((lo4 ^ (k << 4)) + hi2);
        float4 r = *(const float4*)(ldsb + addr);
        r.x *= scale;
        r.y *= scale;
        r.z *= scale;
        r.w *= scale;
        ov[k * 64 + lane] = r;
    }
}

extern "C" void kernel_launch(void* const* d_in, const int* in_sizes, int n_in,
                              void* d_out, int out_size, void* d_ws, size_t ws_size,
                              hipStream_t stream) {
    const float* x = (const float*)d_in[0];
    const float* signs = (const float*)d_in[1];
    float* out = (float*)d_out;
    const int rows = in_sizes[0] / D;  // 8192
    fwht_kernel<<<dim3(rows), dim3(64), 0, stream>>>(x, signs, out);
}